// Round 1
// baseline (725.005 us; speedup 1.0000x reference)
//
#include <hip/hip_runtime.h>
#include <math.h>

#define HW    (512 * 512)
#define FCH   64
#define NB    8
#define NID   32
#define CHUNK 2048
#define PRIV  (33 * 8)   // per-wave private acc: [id 0..32][replica g 0..7], 1056 B

// ---------------------------------------------------------------------------
// Kernel 1: per-instance segment max over encoded [B, F, H, W].
//
// Previous version: ONE shared acc[64][33] updated with ds_atomic_max from all
// waves. Lanes carry random ids 1..32, so each wave-instruction had expected
// max same-address multiplicity ~5-6; same-address LDS atomics serialize at
// full RMW latency per colliding lane => ~300 us (3.5x the HBM floor).
//
// This version: per-WAVE private accumulator priv[33][8], slot = id*8+(lane&7).
//  - same-address collision needs (same id AND same lane-octet): rare (~1/256
//    per lane pair), bank multiplicity ~2-way (free).
//  - waves own channels exclusively (wave w -> f = w*8..w*8+7), so no shared
//    accumulator and only ONE barrier per block (after id staging).
//  - no branches in the hot loop: fmaxf(v,0) makes negative values no-ops
//    under uint-monotone atomicMax; id==0 lands in discarded row 0.
//  - merge per (wave,ch): 1x ds_read_b128 + 3 v_max + shfl_xor(1) + 1 global
//    atomicMax from 32 lanes.
// CHUNK=2048 -> 1024 blocks -> 4 blocks/CU (32 waves/CU) for latency hiding.
// ---------------------------------------------------------------------------
__global__ __launch_bounds__(512) void segmax_kernel(
    const float* __restrict__ encoded,
    const int*   __restrict__ masks,
    float*       __restrict__ vectors)   // [B, NID, F], pre-zeroed
{
    const int b      = blockIdx.y;
    const int chunk0 = blockIdx.x * CHUNK;
    const int tid    = threadIdx.x;
    const int wave   = tid >> 6;
    const int lane   = tid & 63;
    const int g      = lane & 7;

    __shared__ int   ids[CHUNK];         // 8 KB
    __shared__ float priv[8 * PRIV];     // 8.25 KB  (16.25 KB total -> 4 blk/CU)

    // stage ids once: 512 threads x int4 = 2048 ints
    ((int4*)ids)[tid] = ((const int4*)(masks + (size_t)b * HW + chunk0))[tid];
    __syncthreads();

    float* pw = priv + wave * PRIV;
    const float* ebase = encoded + (size_t)b * FCH * HW + chunk0;
    const float4 z4 = make_float4(0.0f, 0.0f, 0.0f, 0.0f);

    for (int k = 0; k < 8; ++k) {
        const int f = wave * 8 + k;
        const float4* src = (const float4*)(ebase + (size_t)f * HW);

        // zero the wave-private 264 slots (wave-private: no barrier needed)
        ((float4*)pw)[lane] = z4;                     // slots 0..255
        if (lane < 2) ((float4*)pw)[64 + lane] = z4;  // slots 256..263
        asm volatile("s_waitcnt lgkmcnt(0)" ::: "memory");  // zeros visible

#pragma unroll
        for (int it = 0; it < CHUNK / 256; ++it) {    // 8 x float4 per lane
            const int idx = it * 64 + lane;
            const float4 v  = src[idx];
            const int4   id = ((const int4*)ids)[idx];
            atomicMax((unsigned*)&pw[(id.x << 3) + g], __float_as_uint(fmaxf(v.x, 0.0f)));
            atomicMax((unsigned*)&pw[(id.y << 3) + g], __float_as_uint(fmaxf(v.y, 0.0f)));
            atomicMax((unsigned*)&pw[(id.z << 3) + g], __float_as_uint(fmaxf(v.z, 0.0f)));
            atomicMax((unsigned*)&pw[(id.w << 3) + g], __float_as_uint(fmaxf(v.w, 0.0f)));
        }
        asm volatile("s_waitcnt lgkmcnt(0)" ::: "memory");  // atomics drained

        // merge: lane L reads slots 8+4L..8+4L+3 (id = 1+(L>>1), g-half 4*(L&1))
        const float4 m4 = ((const float4*)(pw + 8))[lane];
        float m = fmaxf(fmaxf(m4.x, m4.y), fmaxf(m4.z, m4.w));
        m = fmaxf(m, __shfl_xor(m, 1));
        if ((lane & 1) == 0 && m > 0.0f) {
            atomicMax((unsigned*)&vectors[((size_t)b * NID + (lane >> 1)) * FCH + f],
                      __float_as_uint(m));
        }
        asm volatile("s_waitcnt lgkmcnt(0)" ::: "memory");  // reads done before re-zero
    }
}

// ---------------------------------------------------------------------------
// Kernel 2: collapsed pairwise MLP (no nonlinearity between layers):
// out[b,i,j,c] = sigmoid(v_i·A[:,c] + v_j·B[:,c] + cc[c]),
// A = w1[:64]@w2, B = w1[64:]@w2, cc = b1@w2 + b2.
// connections[b, c, j, i] = out[b, i, j, c].      (~5 us, unchanged)
// ---------------------------------------------------------------------------
__global__ __launch_bounds__(256) void conn_kernel(
    const float* __restrict__ vectors,  // [B, NID, F]
    const float* __restrict__ w1,       // [128, 32]
    const float* __restrict__ b1,       // [32]
    const float* __restrict__ w2,       // [32, 4]
    const float* __restrict__ b2,       // [4]
    float*       __restrict__ out)      // [B, 4, NID, NID]
{
    const int b   = blockIdx.x;
    const int tid = threadIdx.x;

    __shared__ float v[NID][FCH];
    __shared__ float A[FCH][4], Bm[FCH][4];
    __shared__ float s[NID][4], t[NID][4];
    __shared__ float cc[4];

    for (int i = tid; i < NID * FCH; i += 256)
        ((float*)v)[i] = vectors[(size_t)b * NID * FCH + i];

    {
        const int k = tid >> 2, c = tid & 3;
        float a = 0.0f, bb = 0.0f;
#pragma unroll
        for (int h = 0; h < 32; ++h) {
            const float w2v = w2[h * 4 + c];
            a  += w1[k * 32 + h]        * w2v;
            bb += w1[(k + 64) * 32 + h] * w2v;
        }
        A[k][c]  = a;
        Bm[k][c] = bb;
        if (tid < 4) {
            float x = b2[tid];
#pragma unroll
            for (int h = 0; h < 32; ++h) x += b1[h] * w2[h * 4 + tid];
            cc[tid] = x;
        }
    }
    __syncthreads();

    if (tid < 128) {
        const int i = tid >> 2, c = tid & 3;
        float a = 0.0f;
#pragma unroll
        for (int f = 0; f < FCH; ++f) a += v[i][f] * A[f][c];
        s[i][c] = a;
    } else {
        const int j = (tid - 128) >> 2, c = tid & 3;
        float a = 0.0f;
#pragma unroll
        for (int f = 0; f < FCH; ++f) a += v[j][f] * Bm[f][c];
        t[j][c] = a;
    }
    __syncthreads();

    for (int o = tid; o < 4 * NID * NID; o += 256) {
        const int i = o & 31;
        const int j = (o >> 5) & 31;
        const int c = o >> 10;
        const float x = s[i][c] + t[j][c] + cc[c];
        out[(((size_t)b * 4 + c) * NID + j) * NID + i] = 1.0f / (1.0f + expf(-x));
    }
}

extern "C" void kernel_launch(void* const* d_in, const int* in_sizes, int n_in,
                              void* d_out, int out_size, void* d_ws, size_t ws_size,
                              hipStream_t stream) {
    const float* encoded = (const float*)d_in[0];
    const int*   masks   = (const int*)d_in[1];
    const float* w1      = (const float*)d_in[2];
    const float* b1      = (const float*)d_in[3];
    const float* w2      = (const float*)d_in[4];
    const float* b2      = (const float*)d_in[5];
    float* out = (float*)d_out;

    float* vectors     = out;                        // NB*NID*FCH = 16384 floats
    float* connections = out + NB * NID * FCH;       // NB*4*NID*NID = 32768 floats

    // vectors must start at 0 (uint-monotone atomicMax; absent id -> 0)
    hipMemsetAsync(vectors, 0, (size_t)NB * NID * FCH * sizeof(float), stream);

    segmax_kernel<<<dim3(HW / CHUNK, NB), 512, 0, stream>>>(encoded, masks, vectors);
    conn_kernel<<<NB, 256, 0, stream>>>(vectors, w1, b1, w2, b2, connections);
}